// Round 8
// baseline (39.563 us; speedup 1.0000x reference)
//
#include <hip/hip_runtime.h>

// Problem constants
#define NB      1024           // graphs
#define NT_     128            // tasks/graph
#define NV_     128            // vehicles/graph
#define NR_     16             // RSUs/graph
#define D_      64             // embed dim
#define H_      32             // hidden
#define NTGT_   144            // NR + NV
#define SCG     18432          // NT_*NTGT_ per graph
#define PWR_OFF 18874368       // NB*SCG
#define NEGV    (-1e9f)
#define EPAD    148            // padded row stride (words) for epilogue LDS tile
#define EWAVE   (8 * EPAD)     // words per wave epilogue region (1184)

typedef __attribute__((ext_vector_type(8))) short  short8;   // 8 bf16 = 4 VGPR
typedef __attribute__((ext_vector_type(4))) float  floatx4;  // MFMA acc / native f32x4

__device__ __forceinline__ unsigned int f2bf_pack(float lo, float hi) {
    unsigned int ul = __float_as_uint(lo);
    ul += 0x7FFFu + ((ul >> 16) & 1u);
    unsigned int uh = __float_as_uint(hi);
    uh += 0x7FFFu + ((uh >> 16) & 1u);
    return (ul >> 16) | (uh & 0xFFFF0000u);
}

extern "C" __global__ void __launch_bounds__(512, 8)
thy_fused(const float* __restrict__ tEmb,          // [NB*NT_, D_]
          const float* __restrict__ gEmb,          // [NB, D_]
          const float* __restrict__ vEmb,          // [NB*NV_, D_]
          const float* __restrict__ rEmb,          // [NB*NR_, D_]
          const int* __restrict__ tMask,           // [NB*NT_]        (bool as int32)
          const int* __restrict__ gMask,           // [NB*NT_, NTGT_] (bool as int32)
          const float* __restrict__ W1,            // [2D_, H_]
          const float* __restrict__ b1,            // [H_]
          const float* __restrict__ W2,            // [H_]
          const float* __restrict__ b2,            // [1]
          float* __restrict__ out)
{
    // staging: bf16 [144][64] swizzled = 18432 B
    // epilogue (after 2nd barrier, reuses buffer): 8 waves * 1184 words * 4B = 37888 B
    __shared__ __align__(16) unsigned char smem[37888];
    const int tid  = threadIdx.x;
    const int b    = blockIdx.x;     // one graph per block
    const int lane = tid & 63;
    const int w    = tid >> 6;       // wave 0..7, owns 16 task rows
    const int ln   = lane & 15;
    const int kg   = lane >> 4;      // 0..3
    const int rbase = w * 16;

    // ---- tMask ballot for this wave's 16 rows (bit q = row rbase+q) ----
    int tmv = (lane < 16) ? tMask[b * NT_ + rbase + lane] : 0;
    unsigned long long tmb = __ballot(tmv != 0);

    // ---- A fragment straight from global: row = w*16 + ln ----
    const float* arow_p = tEmb + ((size_t)b * NT_ + rbase + ln) * D_;
    float4 fa0 = *(const float4*)(arow_p + kg * 8);
    float4 fa1 = *(const float4*)(arow_p + kg * 8 + 4);
    float4 fb0 = *(const float4*)(arow_p + 32 + kg * 8);
    float4 fb1 = *(const float4*)(arow_p + 32 + kg * 8 + 4);

    // ---- stage B (targets = [16 rsu ; 128 veh]) -> [144][64] bf16 swizzled ----
    {
        const float4* rs = (const float4*)(rEmb + (size_t)b * (NR_ * D_));
        const float4* vs = (const float4*)(vEmb + (size_t)b * (NV_ * D_));
        #pragma unroll
        for (int it = 0; it < 5; ++it) {            // 2304 chunks / 512 thr
            int m = tid + it * 512;
            if (m < 2304) {
                int row = m >> 4;
                float4 v = (row < 16) ? rs[m] : vs[m - 256];
                int cb  = (m & 15) << 3;
                int ad  = row * 128 + (cb ^ ((row & 7) << 4));
                uint2 p;
                p.x = f2bf_pack(v.x, v.y);
                p.y = f2bf_pack(v.z, v.w);
                *(uint2*)(smem + ad) = p;
            }
        }
    }

    // pre-scale A by 1/8 (exact: exponent shift) so epilogue needs no scaling,
    // then pack to bf16 while staging loads drain
    union { unsigned int u[4]; short8 s8; } A0, A1;
    A0.u[0] = f2bf_pack(fa0.x * 0.125f, fa0.y * 0.125f);
    A0.u[1] = f2bf_pack(fa0.z * 0.125f, fa0.w * 0.125f);
    A0.u[2] = f2bf_pack(fa1.x * 0.125f, fa1.y * 0.125f);
    A0.u[3] = f2bf_pack(fa1.z * 0.125f, fa1.w * 0.125f);
    A1.u[0] = f2bf_pack(fb0.x * 0.125f, fb0.y * 0.125f);
    A1.u[1] = f2bf_pack(fb0.z * 0.125f, fb0.w * 0.125f);
    A1.u[2] = f2bf_pack(fb1.x * 0.125f, fb1.y * 0.125f);
    A1.u[3] = f2bf_pack(fb1.z * 0.125f, fb1.w * 0.125f);

    __syncthreads();

    floatx4 acc[9] = {};
    #pragma unroll
    for (int s = 0; s < 2; ++s) {          // K = 64 in two K=32 steps
        const int cb = s * 64 + kg * 16;   // byte offset of this lane's 8 bf16
        const short8 av = (s == 0) ? A0.s8 : A1.s8;
        #pragma unroll
        for (int tn = 0; tn < 9; ++tn) {
            int row = tn * 16 + ln;
            short8 bb = *(const short8*)(smem + row * 128 + (cb ^ ((row & 7) << 4)));
            acc[tn] = __builtin_amdgcn_mfma_f32_16x16x32_bf16(av, bb, acc[tn], 0, 0, 0);
        }
    }

    // ---- epilogue: two-pass LDS-bounce -> vectorized mask+store ----
    __syncthreads();                       // all waves done reading B-tile
    float* sc = (float*)smem;
    const int wbase = w * EWAVE;
    const size_t obase = (size_t)b * SCG;
    const int grow0 = b * NT_ + rbase;

    #pragma unroll
    for (int p = 0; p < 2; ++p) {
        // lanes with kg in {2p, 2p+1} own rows [8p, 8p+8) of this m-tile
        // C/D layout: col = lane&15, row = kg*4 + reg  (m89-verified)
        if ((kg >> 1) == p) {
            const int lr = (kg & 1) * 4;
            #pragma unroll
            for (int tn = 0; tn < 9; ++tn) {
                #pragma unroll
                for (int j = 0; j < 4; ++j) {
                    sc[wbase + (lr + j) * EPAD + tn * 16 + ln] = acc[tn][j];
                }
            }
        }
        // same-wave DS ordering: no barrier needed (wave-private region)
        #pragma unroll
        for (int u = 0; u < 5; ++u) {
            int chunk = lane + u * 64;         // 0..287 used (8 rows * 36 f4)
            if (chunk < 288) {
                int row = chunk / 36;
                int c4  = chunk - row * 36;
                int q   = p * 8 + row;                    // row idx within wave tile
                bool trow = (tmb >> q) & 1ull;
                // issue VMEM load first, then DS read: latencies overlap
                int4 gm;
                if (trow)
                    gm = *(const int4*)(gMask + (size_t)(grow0 + q) * NTGT_ + c4 * 4);
                floatx4 sv = *(const floatx4*)(sc + wbase + row * EPAD + c4 * 4);
                floatx4 ov;
                if (trow) {
                    ov[0] = gm.x ? sv[0] : NEGV;
                    ov[1] = gm.y ? sv[1] : NEGV;
                    ov[2] = gm.z ? sv[2] : NEGV;
                    ov[3] = gm.w ? sv[3] : NEGV;
                } else {
                    ov[0] = NEGV; ov[1] = NEGV; ov[2] = NEGV; ov[3] = NEGV;
                }
                __builtin_nontemporal_store(ov,
                    (floatx4*)(out + obase + (size_t)(rbase + q) * NTGT_ + c4 * 4));
            }
        }
    }

    // ---- power head for this graph: wave 0 only (no barriers below) ----
    if (w == 0) {
        const int j  = lane & 31;            // hidden unit
        const int hf = lane >> 5;            // feature half
        const float* fp = (hf == 0) ? (gEmb + (size_t)b * D_)
                                    : (vEmb + (size_t)b * (NV_ * D_));  // veh row 0
        const float* wp = W1 + (size_t)hf * 64 * H_ + j;
        float s = 0.f;
        #pragma unroll
        for (int i = 0; i < 64; ++i)
            s += fp[i] * wp[i * H_];
        s += __shfl_xor(s, 32);              // combine the two halves
        float t = fmaxf(s + b1[j], 0.f) * W2[j];
        t += __shfl_xor(t, 1);
        t += __shfl_xor(t, 2);
        t += __shfl_xor(t, 4);
        t += __shfl_xor(t, 8);
        t += __shfl_xor(t, 16);
        if (lane == 0)
            out[PWR_OFF + b] = 1.0f / (1.0f + expf(-(t + b2[0])));
    }
}

extern "C" void kernel_launch(void* const* d_in, const int* in_sizes, int n_in,
                              void* d_out, int out_size, void* d_ws, size_t ws_size,
                              hipStream_t stream) {
    const float* tEmb = (const float*)d_in[0];
    const float* gEmb = (const float*)d_in[1];
    const float* vEmb = (const float*)d_in[2];
    const float* rEmb = (const float*)d_in[3];
    const int* tMask = (const int*)d_in[4];
    const int* gMask = (const int*)d_in[5];
    const float* W1 = (const float*)d_in[6];
    const float* b1 = (const float*)d_in[7];
    const float* W2 = (const float*)d_in[8];
    const float* b2 = (const float*)d_in[9];
    float* out = (float*)d_out;

    // one block per graph; power head folded into wave 0
    hipLaunchKernelGGL(thy_fused, dim3(NB), dim3(512), 0, stream,
                       tEmb, gEmb, vEmb, rEmb, tMask, gMask, W1, b1, W2, b2, out);
}

// Round 9
// 37.997 us; speedup vs baseline: 1.0412x; 1.0412x over previous
//
#include <hip/hip_runtime.h>

// Problem constants
#define NB      1024           // graphs
#define NT_     128            // tasks/graph
#define NV_     128            // vehicles/graph
#define NR_     16             // RSUs/graph
#define D_      64             // embed dim
#define H_      32             // hidden
#define NTGT_   144            // NR + NV
#define SCG     18432          // NT_*NTGT_ per graph
#define PWR_OFF 18874368       // NB*SCG
#define NEGV    (-1e9f)
#define EPAD    148            // padded row stride (words) for epilogue LDS tile
#define EWAVE   (8 * EPAD)     // words per wave epilogue region (1184)

typedef __attribute__((ext_vector_type(8))) short  short8;   // 8 bf16 = 4 VGPR
typedef __attribute__((ext_vector_type(4))) float  floatx4;  // MFMA acc / native f32x4

__device__ __forceinline__ unsigned int f2bf_pack(float lo, float hi) {
    unsigned int ul = __float_as_uint(lo);
    ul += 0x7FFFu + ((ul >> 16) & 1u);
    unsigned int uh = __float_as_uint(hi);
    uh += 0x7FFFu + ((uh >> 16) & 1u);
    return (ul >> 16) | (uh & 0xFFFF0000u);
}

extern "C" __global__ void __launch_bounds__(512, 8)
thy_fused(const float* __restrict__ tEmb,          // [NB*NT_, D_]
          const float* __restrict__ gEmb,          // [NB, D_]
          const float* __restrict__ vEmb,          // [NB*NV_, D_]
          const float* __restrict__ rEmb,          // [NB*NR_, D_]
          const int* __restrict__ tMask,           // [NB*NT_]        (bool as int32)
          const int* __restrict__ gMask,           // [NB*NT_, NTGT_] (bool as int32)
          const float* __restrict__ W1,            // [2D_, H_]
          const float* __restrict__ b1,            // [H_]
          const float* __restrict__ W2,            // [H_]
          const float* __restrict__ b2,            // [1]
          float* __restrict__ out)
{
    // staging: bf16 [144][64] swizzled = 18432 B
    // epilogue (after 2nd barrier, reuses buffer): 8 waves * 1184 words * 4B = 37888 B
    __shared__ __align__(16) unsigned char smem[37888];
    const int tid  = threadIdx.x;
    const int b    = blockIdx.x;     // one graph per block
    const int lane = tid & 63;
    const int w    = tid >> 6;       // wave 0..7, owns 16 task rows
    const int ln   = lane & 15;
    const int kg   = lane >> 4;      // 0..3

    // ---- A fragment straight from global: row = w*16 + ln ----
    const float* arow_p = tEmb + ((size_t)b * NT_ + w * 16 + ln) * D_;
    float4 fa0 = *(const float4*)(arow_p + kg * 8);
    float4 fa1 = *(const float4*)(arow_p + kg * 8 + 4);
    float4 fb0 = *(const float4*)(arow_p + 32 + kg * 8);
    float4 fb1 = *(const float4*)(arow_p + 32 + kg * 8 + 4);

    // ---- stage B (targets = [16 rsu ; 128 veh]) -> [144][64] bf16 swizzled ----
    {
        const float4* rs = (const float4*)(rEmb + (size_t)b * (NR_ * D_));
        const float4* vs = (const float4*)(vEmb + (size_t)b * (NV_ * D_));
        #pragma unroll
        for (int it = 0; it < 5; ++it) {            // 2304 chunks / 512 thr
            int m = tid + it * 512;
            if (m < 2304) {
                int row = m >> 4;
                float4 v = (row < 16) ? rs[m] : vs[m - 256];
                int cb  = (m & 15) << 3;
                int ad  = row * 128 + (cb ^ ((row & 7) << 4));
                uint2 p;
                p.x = f2bf_pack(v.x, v.y);
                p.y = f2bf_pack(v.z, v.w);
                *(uint2*)(smem + ad) = p;
            }
        }
    }

    // pack A while staging loads drain
    union { unsigned int u[4]; short8 s8; } A0, A1;
    A0.u[0] = f2bf_pack(fa0.x, fa0.y); A0.u[1] = f2bf_pack(fa0.z, fa0.w);
    A0.u[2] = f2bf_pack(fa1.x, fa1.y); A0.u[3] = f2bf_pack(fa1.z, fa1.w);
    A1.u[0] = f2bf_pack(fb0.x, fb0.y); A1.u[1] = f2bf_pack(fb0.z, fb0.w);
    A1.u[2] = f2bf_pack(fb1.x, fb1.y); A1.u[3] = f2bf_pack(fb1.z, fb1.w);

    __syncthreads();

    floatx4 acc[9] = {};
    #pragma unroll
    for (int s = 0; s < 2; ++s) {          // K = 64 in two K=32 steps
        const int cb = s * 64 + kg * 16;   // byte offset of this lane's 8 bf16
        const short8 av = (s == 0) ? A0.s8 : A1.s8;
        #pragma unroll
        for (int tn = 0; tn < 9; ++tn) {
            int row = tn * 16 + ln;
            short8 bb = *(const short8*)(smem + row * 128 + (cb ^ ((row & 7) << 4)));
            acc[tn] = __builtin_amdgcn_mfma_f32_16x16x32_bf16(av, bb, acc[tn], 0, 0, 0);
        }
    }

    // ---- epilogue: two-pass LDS-bounce -> vectorized mask+store ----
    __syncthreads();                       // all waves done reading B-tile
    float* sc = (float*)smem;
    const int wbase = w * EWAVE;
    const size_t obase = (size_t)b * SCG;
    const int rbase = w * 16;

    #pragma unroll
    for (int p = 0; p < 2; ++p) {
        // lanes with kg in {2p, 2p+1} own rows [8p, 8p+8) of this m-tile
        // C/D layout: col = lane&15, row = kg*4 + reg  (m89-verified)
        if ((kg >> 1) == p) {
            const int lr = (kg & 1) * 4;
            #pragma unroll
            for (int tn = 0; tn < 9; ++tn) {
                #pragma unroll
                for (int j = 0; j < 4; ++j) {
                    sc[wbase + (lr + j) * EPAD + tn * 16 + ln] = acc[tn][j] * 0.125f;
                }
            }
        }
        // same-wave DS ordering: no barrier needed (wave-private region)
        #pragma unroll
        for (int u = 0; u < 5; ++u) {
            int chunk = lane + u * 64;         // 0..287 used (8 rows * 36 f4)
            if (chunk < 288) {
                int row = chunk / 36;
                int c4  = chunk - row * 36;
                floatx4 sv = *(const floatx4*)(sc + wbase + row * EPAD + c4 * 4);
                int r    = rbase + p * 8 + row;
                int grow = b * NT_ + r;
                floatx4 ov;
                if (tMask[grow] != 0) {
                    int4 gm = *(const int4*)(gMask + (size_t)grow * NTGT_ + c4 * 4);
                    ov[0] = gm.x ? sv[0] : NEGV;
                    ov[1] = gm.y ? sv[1] : NEGV;
                    ov[2] = gm.z ? sv[2] : NEGV;
                    ov[3] = gm.w ? sv[3] : NEGV;
                } else {
                    ov[0] = NEGV; ov[1] = NEGV; ov[2] = NEGV; ov[3] = NEGV;
                }
                // plain (cached) store this round: testing NT-write-path hypothesis
                *(floatx4*)(out + obase + (size_t)r * NTGT_ + c4 * 4) = ov;
            }
        }
    }

    // ---- power head for this graph: wave 0 only (no barriers below) ----
    if (w == 0) {
        const int j  = lane & 31;            // hidden unit
        const int hf = lane >> 5;            // feature half
        const float* fp = (hf == 0) ? (gEmb + (size_t)b * D_)
                                    : (vEmb + (size_t)b * (NV_ * D_));  // veh row 0
        const float* wp = W1 + (size_t)hf * 64 * H_ + j;
        float s = 0.f;
        #pragma unroll
        for (int i = 0; i < 64; ++i)
            s += fp[i] * wp[i * H_];
        s += __shfl_xor(s, 32);              // combine the two halves
        float t = fmaxf(s + b1[j], 0.f) * W2[j];
        t += __shfl_xor(t, 1);
        t += __shfl_xor(t, 2);
        t += __shfl_xor(t, 4);
        t += __shfl_xor(t, 8);
        t += __shfl_xor(t, 16);
        if (lane == 0)
            out[PWR_OFF + b] = 1.0f / (1.0f + expf(-(t + b2[0])));
    }
}

extern "C" void kernel_launch(void* const* d_in, const int* in_sizes, int n_in,
                              void* d_out, int out_size, void* d_ws, size_t ws_size,
                              hipStream_t stream) {
    const float* tEmb = (const float*)d_in[0];
    const float* gEmb = (const float*)d_in[1];
    const float* vEmb = (const float*)d_in[2];
    const float* rEmb = (const float*)d_in[3];
    const int* tMask = (const int*)d_in[4];
    const int* gMask = (const int*)d_in[5];
    const float* W1 = (const float*)d_in[6];
    const float* b1 = (const float*)d_in[7];
    const float* W2 = (const float*)d_in[8];
    const float* b2 = (const float*)d_in[9];
    float* out = (float*)d_out;

    // one block per graph; power head folded into wave 0
    hipLaunchKernelGGL(thy_fused, dim3(NB), dim3(512), 0, stream,
                       tEmb, gEmb, vEmb, rEmb, tMask, gMask, W1, b1, W2, b2, out);
}

// Round 10
// 34.547 us; speedup vs baseline: 1.1452x; 1.0999x over previous
//
#include <hip/hip_runtime.h>

// Problem constants
#define NB      1024           // graphs
#define NT_     128            // tasks/graph
#define NV_     128            // vehicles/graph
#define NR_     16             // RSUs/graph
#define D_      64             // embed dim
#define H_      32             // hidden
#define NTGT_   144            // NR + NV
#define SCG     18432          // NT_*NTGT_ per graph
#define PWR_OFF 18874368       // NB*SCG
#define NEGV    (-1e9f)
#define EPADH   152            // padded row stride (bf16 units) for epilogue tile
#define EWAVEH  (16 * EPADH)   // bf16 units per wave epilogue region (2432)

typedef __attribute__((ext_vector_type(8))) short  short8;   // 8 bf16 = 4 VGPR
typedef __attribute__((ext_vector_type(4))) float  floatx4;  // MFMA acc / native f32x4

__device__ __forceinline__ unsigned int f2bf_pack(float lo, float hi) {
    unsigned int ul = __float_as_uint(lo);
    ul += 0x7FFFu + ((ul >> 16) & 1u);
    unsigned int uh = __float_as_uint(hi);
    uh += 0x7FFFu + ((uh >> 16) & 1u);
    return (ul >> 16) | (uh & 0xFFFF0000u);
}

__device__ __forceinline__ unsigned short f2bf1(float x) {
    unsigned int u = __float_as_uint(x);
    u += 0x7FFFu + ((u >> 16) & 1u);
    return (unsigned short)(u >> 16);
}

__device__ __forceinline__ float bf2f(unsigned short h) {
    return __uint_as_float((unsigned int)h << 16);
}

extern "C" __global__ void __launch_bounds__(512, 8)
thy_fused(const float* __restrict__ tEmb,          // [NB*NT_, D_]
          const float* __restrict__ gEmb,          // [NB, D_]
          const float* __restrict__ vEmb,          // [NB*NV_, D_]
          const float* __restrict__ rEmb,          // [NB*NR_, D_]
          const int* __restrict__ tMask,           // [NB*NT_]        (bool as int32)
          const int* __restrict__ gMask,           // [NB*NT_, NTGT_] (bool as int32)
          const float* __restrict__ W1,            // [2D_, H_]
          const float* __restrict__ b1,            // [H_]
          const float* __restrict__ W2,            // [H_]
          const float* __restrict__ b2,            // [1]
          float* __restrict__ out)
{
    // staging: bf16 [144][64] swizzled = 18432 B
    // epilogue (after 2nd barrier, reuses buffer): 8 waves * 2432 bf16 * 2B = 38912 B
    __shared__ __align__(16) unsigned char smem[38912];
    const int tid  = threadIdx.x;
    const int b    = blockIdx.x;     // one graph per block
    const int lane = tid & 63;
    const int w    = tid >> 6;       // wave 0..7, owns 16 task rows
    const int ln   = lane & 15;
    const int kg   = lane >> 4;      // 0..3
    const int rbase = w * 16;

    // ---- A fragment straight from global: row = w*16 + ln ----
    const float* arow_p = tEmb + ((size_t)b * NT_ + rbase + ln) * D_;
    float4 fa0 = *(const float4*)(arow_p + kg * 8);
    float4 fa1 = *(const float4*)(arow_p + kg * 8 + 4);
    float4 fb0 = *(const float4*)(arow_p + 32 + kg * 8);
    float4 fb1 = *(const float4*)(arow_p + 32 + kg * 8 + 4);

    // ---- stage B (targets = [16 rsu ; 128 veh]) -> [144][64] bf16 swizzled ----
    {
        const float4* rs = (const float4*)(rEmb + (size_t)b * (NR_ * D_));
        const float4* vs = (const float4*)(vEmb + (size_t)b * (NV_ * D_));
        #pragma unroll
        for (int it = 0; it < 5; ++it) {            // 2304 chunks / 512 thr
            int m = tid + it * 512;
            if (m < 2304) {
                int row = m >> 4;
                float4 v = (row < 16) ? rs[m] : vs[m - 256];
                int cb  = (m & 15) << 3;
                int ad  = row * 128 + (cb ^ ((row & 7) << 4));
                uint2 p;
                p.x = f2bf_pack(v.x, v.y);
                p.y = f2bf_pack(v.z, v.w);
                *(uint2*)(smem + ad) = p;
            }
        }
    }

    // pack A while staging loads drain
    union { unsigned int u[4]; short8 s8; } A0, A1;
    A0.u[0] = f2bf_pack(fa0.x, fa0.y); A0.u[1] = f2bf_pack(fa0.z, fa0.w);
    A0.u[2] = f2bf_pack(fa1.x, fa1.y); A0.u[3] = f2bf_pack(fa1.z, fa1.w);
    A1.u[0] = f2bf_pack(fb0.x, fb0.y); A1.u[1] = f2bf_pack(fb0.z, fb0.w);
    A1.u[2] = f2bf_pack(fb1.x, fb1.y); A1.u[3] = f2bf_pack(fb1.z, fb1.w);

    __syncthreads();

    floatx4 acc[9] = {};
    #pragma unroll
    for (int s = 0; s < 2; ++s) {          // K = 64 in two K=32 steps
        const int cb = s * 64 + kg * 16;   // byte offset of this lane's 8 bf16
        const short8 av = (s == 0) ? A0.s8 : A1.s8;
        #pragma unroll
        for (int tn = 0; tn < 9; ++tn) {
            int row = tn * 16 + ln;
            short8 bb = *(const short8*)(smem + row * 128 + (cb ^ ((row & 7) << 4)));
            acc[tn] = __builtin_amdgcn_mfma_f32_16x16x32_bf16(av, bb, acc[tn], 0, 0, 0);
        }
    }

    // ---- epilogue: single-pass 16-row bf16 LDS bounce -> vectorized mask+store ----
    __syncthreads();                       // all waves done reading B-tile
    unsigned short* sc = (unsigned short*)smem;
    const int wb = w * EWAVEH;
    const size_t obase = (size_t)b * SCG;

    // write all 16 rows of this wave's C tile as bf16 (scaled by 1/8)
    // C/D layout: col = lane&15, row = kg*4 + reg  (m89-verified)
    #pragma unroll
    for (int tn = 0; tn < 9; ++tn) {
        #pragma unroll
        for (int j = 0; j < 4; ++j) {
            sc[wb + (kg * 4 + j) * EPADH + tn * 16 + ln] = f2bf1(acc[tn][j] * 0.125f);
        }
    }

    // same-wave DS ordering: no barrier needed (wave-private region)
    #pragma unroll
    for (int u = 0; u < 9; ++u) {
        int chunk = lane + u * 64;         // 0..575, exactly 16 rows * 36 chunks
        int row   = chunk / 36;
        int c4    = chunk - row * 36;
        ushort4 hv = *(const ushort4*)(sc + wb + row * EPADH + c4 * 4);
        int r    = rbase + row;
        int grow = b * NT_ + r;
        floatx4 ov;
        if (tMask[grow] != 0) {
            int4 gm = *(const int4*)(gMask + (size_t)grow * NTGT_ + c4 * 4);
            ov[0] = gm.x ? bf2f(hv.x) : NEGV;
            ov[1] = gm.y ? bf2f(hv.y) : NEGV;
            ov[2] = gm.z ? bf2f(hv.z) : NEGV;
            ov[3] = gm.w ? bf2f(hv.w) : NEGV;
        } else {
            ov[0] = NEGV; ov[1] = NEGV; ov[2] = NEGV; ov[3] = NEGV;
        }
        __builtin_nontemporal_store(ov,
            (floatx4*)(out + obase + (size_t)r * NTGT_ + c4 * 4));
    }

    // ---- power head for this graph: wave 0 only (no barriers below) ----
    if (w == 0) {
        const int j  = lane & 31;            // hidden unit
        const int hf = lane >> 5;            // feature half
        const float* fp = (hf == 0) ? (gEmb + (size_t)b * D_)
                                    : (vEmb + (size_t)b * (NV_ * D_));  // veh row 0
        const float* wp = W1 + (size_t)hf * 64 * H_ + j;
        float s = 0.f;
        #pragma unroll
        for (int i = 0; i < 64; ++i)
            s += fp[i] * wp[i * H_];
        s += __shfl_xor(s, 32);              // combine the two halves
        float t = fmaxf(s + b1[j], 0.f) * W2[j];
        t += __shfl_xor(t, 1);
        t += __shfl_xor(t, 2);
        t += __shfl_xor(t, 4);
        t += __shfl_xor(t, 8);
        t += __shfl_xor(t, 16);
        if (lane == 0)
            out[PWR_OFF + b] = 1.0f / (1.0f + expf(-(t + b2[0])));
    }
}

extern "C" void kernel_launch(void* const* d_in, const int* in_sizes, int n_in,
                              void* d_out, int out_size, void* d_ws, size_t ws_size,
                              hipStream_t stream) {
    const float* tEmb = (const float*)d_in[0];
    const float* gEmb = (const float*)d_in[1];
    const float* vEmb = (const float*)d_in[2];
    const float* rEmb = (const float*)d_in[3];
    const int* tMask = (const int*)d_in[4];
    const int* gMask = (const int*)d_in[5];
    const float* W1 = (const float*)d_in[6];
    const float* b1 = (const float*)d_in[7];
    const float* W2 = (const float*)d_in[8];
    const float* b2 = (const float*)d_in[9];
    float* out = (float*)d_out;

    // one block per graph; power head folded into wave 0
    hipLaunchKernelGGL(thy_fused, dim3(NB), dim3(512), 0, stream,
                       tEmb, gEmb, vEmb, rEmb, tMask, gMask, W1, b1, W2, b2, out);
}